// Round 2
// baseline (401.412 us; speedup 1.0000x reference)
//
#include <hip/hip_runtime.h>
#include <hip/hip_bf16.h>

#define T_SEQ   2048
#define BATCH   2
#define DMODEL  1024
#define NHEADS  16
#define HDIM    64
#define WINDOW  128

typedef __attribute__((ext_vector_type(8))) short bf16x8;
typedef __attribute__((ext_vector_type(4))) float f32x4;

__device__ inline void unpack8(uint4 u, float* f) {
    unsigned int w[4] = {u.x, u.y, u.z, u.w};
#pragma unroll
    for (int i = 0; i < 4; i++) {
        f[2*i]   = __uint_as_float(w[i] << 16);
        f[2*i+1] = __uint_as_float(w[i] & 0xffff0000u);
    }
}

// Load 16 contiguous elements starting at p+off, as bf16 packed array.
__device__ inline void load16_f32_to_bf16(const float* p, __hip_bfloat16* dst) {
    float4 f0 = *(const float4*)(p);
    float4 f1 = *(const float4*)(p + 4);
    float4 f2 = *(const float4*)(p + 8);
    float4 f3 = *(const float4*)(p + 12);
    float v[16] = {f0.x,f0.y,f0.z,f0.w, f1.x,f1.y,f1.z,f1.w,
                   f2.x,f2.y,f2.z,f2.w, f3.x,f3.y,f3.z,f3.w};
#pragma unroll
    for (int i = 0; i < 16; i++) dst[i] = __float2bfloat16(v[i]);
}

__device__ inline void load16_bf16(const __hip_bfloat16* p, __hip_bfloat16* dst) {
    *(uint4*)dst       = *(const uint4*)p;
    *(uint4*)(dst + 8) = *(const uint4*)(p + 8);
}

// C[M,N] = A[M,K] * W[N,K]^T  (torch Linear). W is always fp32.
// A: fp32 if A_F32 else bf16. C: fp32 if C_F32 else bf16.
// blockIdx.z selects (W0,C0)/(W1,C1)/(W2,C2).
// 128x128 tile, BK=32, 4 waves (2x2 of 64x64), 16x16x32 bf16 MFMA.
template<bool A_F32, bool C_F32>
__global__ __launch_bounds__(256) void gemm_bt_kernel(
    const void* __restrict__ Av,
    const float* __restrict__ W0,
    const float* __restrict__ W1,
    const float* __restrict__ W2,
    void* __restrict__ C0v,
    void* __restrict__ C1v,
    void* __restrict__ C2v,
    int M, int N, int K)
{
    const int z = blockIdx.z;
    const float* W = (z == 0) ? W0 : (z == 1 ? W1 : W2);
    void* Cv = (z == 0) ? C0v : (z == 1 ? C1v : C2v);

    const int n0 = blockIdx.x * 128;
    const int m0 = blockIdx.y * 128;

    // padded stride 40 elems (80B): bank step 20 -> 2-way aliasing (free)
    __shared__ __hip_bfloat16 As[128 * 40];
    __shared__ __hip_bfloat16 Bs[128 * 40];

    const int t    = threadIdx.x;
    const int r    = t >> 1;          // staging row 0..127
    const int ch   = (t & 1) * 16;    // staging col-chunk 0 or 16

    const int lane = t & 63;
    const int wv   = t >> 6;          // wave 0..3
    const int wm   = (wv >> 1) * 64;
    const int wn   = (wv & 1) * 64;
    const int lrow = lane & 15;
    const int quad = lane >> 4;

    f32x4 acc[4][4];
#pragma unroll
    for (int i = 0; i < 4; i++)
#pragma unroll
        for (int j = 0; j < 4; j++)
            acc[i][j] = (f32x4){0.f, 0.f, 0.f, 0.f};

    const float* Ap_f = A_F32 ? ((const float*)Av + (size_t)(m0 + r) * K + ch) : nullptr;
    const __hip_bfloat16* Ap_b = A_F32 ? nullptr
                                       : ((const __hip_bfloat16*)Av + (size_t)(m0 + r) * K + ch);
    const float* Wp = W + (size_t)(n0 + r) * K + ch;
    __hip_bfloat16* AsW = &As[r * 40 + ch];
    __hip_bfloat16* BsW = &Bs[r * 40 + ch];

    for (int k0 = 0; k0 < K; k0 += 32) {
        __hip_bfloat16 at[16], bt[16];
        if (A_F32) load16_f32_to_bf16(Ap_f + k0, at);
        else       load16_bf16(Ap_b + k0, at);
        load16_f32_to_bf16(Wp + k0, bt);
        *(uint4*)(AsW)     = *(uint4*)at;
        *(uint4*)(AsW + 8) = *(uint4*)(at + 8);
        *(uint4*)(BsW)     = *(uint4*)bt;
        *(uint4*)(BsW + 8) = *(uint4*)(bt + 8);
        __syncthreads();

        bf16x8 af[4], bfv[4];
#pragma unroll
        for (int mi = 0; mi < 4; mi++)
            af[mi] = *(const bf16x8*)&As[(wm + mi * 16 + lrow) * 40 + quad * 8];
#pragma unroll
        for (int ni = 0; ni < 4; ni++)
            bfv[ni] = *(const bf16x8*)&Bs[(wn + ni * 16 + lrow) * 40 + quad * 8];
#pragma unroll
        for (int mi = 0; mi < 4; mi++)
#pragma unroll
            for (int ni = 0; ni < 4; ni++)
                acc[mi][ni] = __builtin_amdgcn_mfma_f32_16x16x32_bf16(
                    af[mi], bfv[ni], acc[mi][ni], 0, 0, 0);
        __syncthreads();
    }

    // epilogue: C/D layout col=lane&15, row=quad*4+reg  [verified m89/m91]
#pragma unroll
    for (int mi = 0; mi < 4; mi++) {
#pragma unroll
        for (int rr = 0; rr < 4; rr++) {
            int row = m0 + wm + mi * 16 + quad * 4 + rr;
            if (C_F32) {
                float* Crow = (float*)Cv + (size_t)row * N + n0 + wn + lrow;
#pragma unroll
                for (int ni = 0; ni < 4; ni++)
                    Crow[ni * 16] = acc[mi][ni][rr];
            } else {
                __hip_bfloat16* Crow = (__hip_bfloat16*)Cv + (size_t)row * N + n0 + wn + lrow;
#pragma unroll
                for (int ni = 0; ni < 4; ni++)
                    Crow[ni * 16] = __float2bfloat16(acc[mi][ni][rr]);
            }
        }
    }
}

// In-place per-head l2 normalize of Q and K (bf16 ws buffers).
// One wave per (b,t) row of 1024; lane covers [lane*16, lane*16+16);
// head = lane>>2 (4 lanes/head, 64 elems/head).
__global__ __launch_bounds__(256) void l2norm_kernel(__hip_bfloat16* Q, __hip_bfloat16* Kb)
{
    int gw   = (blockIdx.x * 256 + threadIdx.x) >> 6;   // 0..8191
    int lane = threadIdx.x & 63;
    __hip_bfloat16* buf = (gw < 4096) ? Q : Kb;
    int row = gw & 4095;
    __hip_bfloat16* p = buf + (size_t)row * DMODEL + lane * 16;

    uint4 u0 = *(uint4*)p;
    uint4 u1 = *(uint4*)(p + 8);
    float v[16];
    unpack8(u0, v);
    unpack8(u1, v + 8);
    float ss = 0.f;
#pragma unroll
    for (int i = 0; i < 16; i++) ss += v[i] * v[i];
    ss += __shfl_xor(ss, 1);
    ss += __shfl_xor(ss, 2);
    float inv = 1.0f / fmaxf(sqrtf(ss), 1e-6f);
    __hip_bfloat16 pk[16];
#pragma unroll
    for (int i = 0; i < 16; i++) pk[i] = __float2bfloat16(v[i] * inv);
    *(uint4*)p       = *(uint4*)pk;
    *(uint4*)(p + 8) = *(uint4*)(pk + 8);
}

// Sliding-window attention (window is FORWARD: keys j in [i, i+127]).
// Block = 256 threads handles one (b,h) x 64-query tile.
// thread = (query qi = t>>2, key-slot = t&3): each thread does 32 keys,
// 4-lane shuffle groups reduce softmax stats and the output.
__global__ __launch_bounds__(256) void attn_kernel(
    const __hip_bfloat16* __restrict__ Q,
    const __hip_bfloat16* __restrict__ K,
    const __hip_bfloat16* __restrict__ V,
    __hip_bfloat16* __restrict__ O)
{
    const int i0 = blockIdx.x * 64;
    const int h  = blockIdx.y;
    const int b  = blockIdx.z;

    // band of 191 keys (rows 0..190), padded stride 72 elems
    __shared__ __hip_bfloat16 Ks[192 * 72];
    __shared__ __hip_bfloat16 Vs[192 * 72];

    const size_t base = ((size_t)b * T_SEQ) * DMODEL + h * HDIM;

    for (int vv = threadIdx.x; vv < 192 * 8; vv += 256) {
        int row = vv >> 3;
        int e0  = (vv & 7) * 8;
        int j   = min(i0 + row, T_SEQ - 1);    // clamp; masked later
        *(uint4*)&Ks[row * 72 + e0] = *(const uint4*)(K + base + (size_t)j * DMODEL + e0);
        *(uint4*)&Vs[row * 72 + e0] = *(const uint4*)(V + base + (size_t)j * DMODEL + e0);
    }
    __syncthreads();

    const int qi   = threadIdx.x >> 2;
    const int slot = threadIdx.x & 3;
    const int iq   = i0 + qi;
    const float slope = exp2f(-8.0f * (float)h / 15.0f);

    float q[64];
    {
        const __hip_bfloat16* qp = Q + base + (size_t)iq * DMODEL;
#pragma unroll
        for (int c = 0; c < 8; c++) {
            uint4 u = *(const uint4*)(qp + c * 8);
            unpack8(u, &q[c * 8]);
        }
    }

    float sc[32];
#pragma unroll
    for (int s = 0; s < 32; s++) {
        int jj = slot + s * 4;                 // rel = j - i in [0,127]
        float dot = 0.f;
        const __hip_bfloat16* kr = &Ks[(qi + jj) * 72];
#pragma unroll
        for (int c = 0; c < 8; c++) {
            uint4 u = *(const uint4*)(kr + c * 8);
            float kv[8];
            unpack8(u, kv);
#pragma unroll
            for (int e = 0; e < 8; e++) dot += q[c * 8 + e] * kv[e];
        }
        sc[s] = (iq + jj < T_SEQ) ? (dot - (float)jj * slope) : -1e30f;
    }

    float m = sc[0];
#pragma unroll
    for (int s = 1; s < 32; s++) m = fmaxf(m, sc[s]);
    m = fmaxf(m, __shfl_xor(m, 1));
    m = fmaxf(m, __shfl_xor(m, 2));

    float sum = 0.f;
#pragma unroll
    for (int s = 0; s < 32; s++) {
        sc[s] = __expf(sc[s] - m);
        sum += sc[s];
    }
    sum += __shfl_xor(sum, 1);
    sum += __shfl_xor(sum, 2);
    float rden = 1.0f / sum;

    float out[64];
#pragma unroll
    for (int e = 0; e < 64; e++) out[e] = 0.f;
#pragma unroll
    for (int s = 0; s < 32; s++) {
        float p = sc[s];
        const __hip_bfloat16* vr = &Vs[(qi + slot + s * 4) * 72];
#pragma unroll
        for (int c = 0; c < 8; c++) {
            uint4 u = *(const uint4*)(vr + c * 8);
            float vvv[8];
            unpack8(u, vvv);
#pragma unroll
            for (int e = 0; e < 8; e++) out[c * 8 + e] += p * vvv[e];
        }
    }
#pragma unroll
    for (int e = 0; e < 64; e++) {
        out[e] += __shfl_xor(out[e], 1);
        out[e] += __shfl_xor(out[e], 2);
    }

    __hip_bfloat16* op = O + base + (size_t)iq * DMODEL + slot * 16;
    __hip_bfloat16 pk[16];
#pragma unroll
    for (int e = 0; e < 16; e++) pk[e] = __float2bfloat16(out[slot * 16 + e] * rden);
    *(uint4*)op       = *(uint4*)pk;
    *(uint4*)(op + 8) = *(uint4*)(pk + 8);
}

extern "C" void kernel_launch(void* const* d_in, const int* in_sizes, int n_in,
                              void* d_out, int out_size, void* d_ws, size_t ws_size,
                              hipStream_t stream)
{
    const float* x  = (const float*)d_in[0];
    const float* Wq = (const float*)d_in[1];
    const float* Wk = (const float*)d_in[2];
    const float* Wv = (const float*)d_in[3];
    const float* Wo = (const float*)d_in[4];
    float* out = (float*)d_out;

    const size_t MT = (size_t)BATCH * T_SEQ;          // 4096 rows
    __hip_bfloat16* Qw = (__hip_bfloat16*)d_ws;       // 8 MB each (bf16)
    __hip_bfloat16* Kw = Qw + MT * DMODEL;
    __hip_bfloat16* Vw = Kw + MT * DMODEL;
    __hip_bfloat16* AO = Vw + MT * DMODEL;

    dim3 g1(DMODEL / 128, MT / 128, 3);
    gemm_bt_kernel<true, false><<<g1, 256, 0, stream>>>(
        x, Wq, Wk, Wv, Qw, Kw, Vw, (int)MT, DMODEL, DMODEL);

    l2norm_kernel<<<2048, 256, 0, stream>>>(Qw, Kw);

    dim3 g2(T_SEQ / 64, NHEADS, BATCH);
    attn_kernel<<<g2, 256, 0, stream>>>(Qw, Kw, Vw, AO);

    dim3 g3(DMODEL / 128, MT / 128, 1);
    gemm_bt_kernel<false, true><<<g3, 256, 0, stream>>>(
        AO, Wo, Wo, Wo, out, out, out, (int)MT, DMODEL, DMODEL);
}

// Round 3
// 237.325 us; speedup vs baseline: 1.6914x; 1.6914x over previous
//
#include <hip/hip_runtime.h>
#include <hip/hip_bf16.h>

#define T_SEQ   2048
#define BATCH   2
#define DMODEL  1024
#define NHEADS  16
#define HDIM    64
#define WINDOW  128

typedef __attribute__((ext_vector_type(8))) short bf16x8;
typedef __attribute__((ext_vector_type(4))) float f32x4;

__device__ inline void unpack8(uint4 u, float* f) {
    unsigned int w[4] = {u.x, u.y, u.z, u.w};
#pragma unroll
    for (int i = 0; i < 4; i++) {
        f[2*i]   = __uint_as_float(w[i] << 16);
        f[2*i+1] = __uint_as_float(w[i] & 0xffff0000u);
    }
}

// Load 16 contiguous fp32 elements, convert to packed bf16.
__device__ inline void load16_f32_to_bf16(const float* p, __hip_bfloat16* dst) {
    float4 f0 = *(const float4*)(p);
    float4 f1 = *(const float4*)(p + 4);
    float4 f2 = *(const float4*)(p + 8);
    float4 f3 = *(const float4*)(p + 12);
    float v[16] = {f0.x,f0.y,f0.z,f0.w, f1.x,f1.y,f1.z,f1.w,
                   f2.x,f2.y,f2.z,f2.w, f3.x,f3.y,f3.z,f3.w};
#pragma unroll
    for (int i = 0; i < 16; i++) dst[i] = __float2bfloat16(v[i]);
}

__device__ inline void load16_bf16(const __hip_bfloat16* p, __hip_bfloat16* dst) {
    *(uint4*)dst       = *(const uint4*)p;
    *(uint4*)(dst + 8) = *(const uint4*)(p + 8);
}

// C[M,N] = A[M,K] * W[N,K]^T  (torch Linear). W is always fp32.
// A: fp32 if A_F32 else bf16. C: fp32 if C_F32 else bf16.
// blockIdx.z selects (W0,C0)/(W1,C1)/(W2,C2).
// 128x128 tile, BK=32, 4 waves (2x2 of 64x64), 16x16x32 bf16 MFMA.
template<bool A_F32, bool C_F32>
__global__ __launch_bounds__(256) void gemm_bt_kernel(
    const void* __restrict__ Av,
    const float* __restrict__ W0,
    const float* __restrict__ W1,
    const float* __restrict__ W2,
    void* __restrict__ C0v,
    void* __restrict__ C1v,
    void* __restrict__ C2v,
    int M, int N, int K)
{
    const int z = blockIdx.z;
    const float* W = (z == 0) ? W0 : (z == 1 ? W1 : W2);
    void* Cv = (z == 0) ? C0v : (z == 1 ? C1v : C2v);

    const int n0 = blockIdx.x * 128;
    const int m0 = blockIdx.y * 128;

    // padded stride 40 elems (80B): bank step 20 -> 2-way aliasing (free)
    __shared__ __hip_bfloat16 As[128 * 40];
    __shared__ __hip_bfloat16 Bs[128 * 40];

    const int t    = threadIdx.x;
    const int r    = t >> 1;          // staging row 0..127
    const int ch   = (t & 1) * 16;    // staging col-chunk 0 or 16

    const int lane = t & 63;
    const int wv   = t >> 6;          // wave 0..3
    const int wm   = (wv >> 1) * 64;
    const int wn   = (wv & 1) * 64;
    const int lrow = lane & 15;
    const int quad = lane >> 4;

    f32x4 acc[4][4];
#pragma unroll
    for (int i = 0; i < 4; i++)
#pragma unroll
        for (int j = 0; j < 4; j++)
            acc[i][j] = (f32x4){0.f, 0.f, 0.f, 0.f};

    const float* Ap_f = A_F32 ? ((const float*)Av + (size_t)(m0 + r) * K + ch) : nullptr;
    const __hip_bfloat16* Ap_b = A_F32 ? nullptr
                                       : ((const __hip_bfloat16*)Av + (size_t)(m0 + r) * K + ch);
    const float* Wp = W + (size_t)(n0 + r) * K + ch;
    __hip_bfloat16* AsW = &As[r * 40 + ch];
    __hip_bfloat16* BsW = &Bs[r * 40 + ch];

    for (int k0 = 0; k0 < K; k0 += 32) {
        __hip_bfloat16 at[16], bt[16];
        if (A_F32) load16_f32_to_bf16(Ap_f + k0, at);
        else       load16_bf16(Ap_b + k0, at);
        load16_f32_to_bf16(Wp + k0, bt);
        *(uint4*)(AsW)     = *(uint4*)at;
        *(uint4*)(AsW + 8) = *(uint4*)(at + 8);
        *(uint4*)(BsW)     = *(uint4*)bt;
        *(uint4*)(BsW + 8) = *(uint4*)(bt + 8);
        __syncthreads();

        bf16x8 af[4], bfv[4];
#pragma unroll
        for (int mi = 0; mi < 4; mi++)
            af[mi] = *(const bf16x8*)&As[(wm + mi * 16 + lrow) * 40 + quad * 8];
#pragma unroll
        for (int ni = 0; ni < 4; ni++)
            bfv[ni] = *(const bf16x8*)&Bs[(wn + ni * 16 + lrow) * 40 + quad * 8];
#pragma unroll
        for (int mi = 0; mi < 4; mi++)
#pragma unroll
            for (int ni = 0; ni < 4; ni++)
                acc[mi][ni] = __builtin_amdgcn_mfma_f32_16x16x32_bf16(
                    af[mi], bfv[ni], acc[mi][ni], 0, 0, 0);
        __syncthreads();
    }

    // epilogue: C/D layout col=lane&15, row=quad*4+reg  [verified m89/m91]
#pragma unroll
    for (int mi = 0; mi < 4; mi++) {
#pragma unroll
        for (int rr = 0; rr < 4; rr++) {
            int row = m0 + wm + mi * 16 + quad * 4 + rr;
            if (C_F32) {
                float* Crow = (float*)Cv + (size_t)row * N + n0 + wn + lrow;
#pragma unroll
                for (int ni = 0; ni < 4; ni++)
                    Crow[ni * 16] = acc[mi][ni][rr];
            } else {
                __hip_bfloat16* Crow = (__hip_bfloat16*)Cv + (size_t)row * N + n0 + wn + lrow;
#pragma unroll
                for (int ni = 0; ni < 4; ni++)
                    Crow[ni * 16] = __float2bfloat16(acc[mi][ni][rr]);
            }
        }
    }
}

// In-place per-head l2 normalize of Q and K (bf16 ws buffers).
__global__ __launch_bounds__(256) void l2norm_kernel(__hip_bfloat16* Q, __hip_bfloat16* Kb)
{
    int gw   = (blockIdx.x * 256 + threadIdx.x) >> 6;   // 0..8191
    int lane = threadIdx.x & 63;
    __hip_bfloat16* buf = (gw < 4096) ? Q : Kb;
    int row = gw & 4095;
    __hip_bfloat16* p = buf + (size_t)row * DMODEL + lane * 16;

    uint4 u0 = *(uint4*)p;
    uint4 u1 = *(uint4*)(p + 8);
    float v[16];
    unpack8(u0, v);
    unpack8(u1, v + 8);
    float ss = 0.f;
#pragma unroll
    for (int i = 0; i < 16; i++) ss += v[i] * v[i];
    ss += __shfl_xor(ss, 1);
    ss += __shfl_xor(ss, 2);
    float inv = 1.0f / fmaxf(sqrtf(ss), 1e-6f);
    __hip_bfloat16 pk[16];
#pragma unroll
    for (int i = 0; i < 16; i++) pk[i] = __float2bfloat16(v[i] * inv);
    *(uint4*)p       = *(uint4*)pk;
    *(uint4*)(p + 8) = *(uint4*)(pk + 8);
}

// Sliding-window attention, two-phase to keep VGPRs < 128 (no spills).
// Block = 256 threads = one (b,h) x 64-query tile; thread=(qi=t>>2, slot=t&3).
// Phase 1: scores + softmax for 32 keys/thread -> normalized p into LDS
//          (overlaid on the dead Ks buffer, bf16, stride 136).
// Phase 2: each thread accumulates its 16 output elems over all 128 keys.
__global__ __launch_bounds__(256) void attn_kernel(
    const __hip_bfloat16* __restrict__ Q,
    const __hip_bfloat16* __restrict__ K,
    const __hip_bfloat16* __restrict__ V,
    __hip_bfloat16* __restrict__ O)
{
    const int i0 = blockIdx.x * 64;
    const int h  = blockIdx.y;
    const int b  = blockIdx.z;

    // band of 191 keys (rows 0..190), padded stride 72 elems
    __shared__ __hip_bfloat16 KP[192 * 72];   // Ks in phase 1, P overlay in phase 2
    __shared__ __hip_bfloat16 Vs[192 * 72];

    const size_t base = ((size_t)b * T_SEQ) * DMODEL + h * HDIM;

    for (int vv = threadIdx.x; vv < 192 * 8; vv += 256) {
        int row = vv >> 3;
        int e0  = (vv & 7) * 8;
        int j   = min(i0 + row, T_SEQ - 1);    // clamp; masked later
        *(uint4*)&KP[row * 72 + e0] = *(const uint4*)(K + base + (size_t)j * DMODEL + e0);
        *(uint4*)&Vs[row * 72 + e0] = *(const uint4*)(V + base + (size_t)j * DMODEL + e0);
    }
    __syncthreads();

    const int qi   = threadIdx.x >> 2;
    const int slot = threadIdx.x & 3;
    const int iq   = i0 + qi;
    const float slope = exp2f(-8.0f * (float)h / 15.0f);

    float q[64];
    {
        const __hip_bfloat16* qp = Q + base + (size_t)iq * DMODEL;
#pragma unroll
        for (int c = 0; c < 8; c++) {
            uint4 u = *(const uint4*)(qp + c * 8);
            unpack8(u, &q[c * 8]);
        }
    }

    float sc[32];
#pragma unroll
    for (int s = 0; s < 32; s++) {
        int jj = slot + s * 4;                 // rel = j - i in [0,127]
        float dot = 0.f;
        const __hip_bfloat16* kr = &KP[(qi + jj) * 72];
#pragma unroll
        for (int c = 0; c < 8; c++) {
            uint4 u = *(const uint4*)(kr + c * 8);
            float kv[8];
            unpack8(u, kv);
#pragma unroll
            for (int e = 0; e < 8; e++) dot += q[c * 8 + e] * kv[e];
        }
        sc[s] = (iq + jj < T_SEQ) ? (dot - (float)jj * slope) : -1e30f;
    }

    float m = sc[0];
#pragma unroll
    for (int s = 1; s < 32; s++) m = fmaxf(m, sc[s]);
    m = fmaxf(m, __shfl_xor(m, 1));
    m = fmaxf(m, __shfl_xor(m, 2));

    float sum = 0.f;
#pragma unroll
    for (int s = 0; s < 32; s++) {
        sc[s] = __expf(sc[s] - m);
        sum += sc[s];
    }
    sum += __shfl_xor(sum, 1);
    sum += __shfl_xor(sum, 2);
    float rden = 1.0f / sum;

    // all K reads done -> safe to overlay P into KP
    __syncthreads();
#pragma unroll
    for (int s = 0; s < 32; s++)
        KP[qi * 136 + slot + s * 4] = __float2bfloat16(sc[s] * rden);
    __syncthreads();

    // phase 2: out[e] = sum_j p[j] * V[qi+j][slot*16+e],  e in [0,16)
    float out[16];
#pragma unroll
    for (int e = 0; e < 16; e++) out[e] = 0.f;

    for (int j0 = 0; j0 < 128; j0 += 8) {
        uint4 pu = *(const uint4*)&KP[qi * 136 + j0];   // 8 probs, broadcast across slots
        float p8[8];
        unpack8(pu, p8);
#pragma unroll
        for (int jj = 0; jj < 8; jj++) {
            const __hip_bfloat16* vr = &Vs[(qi + j0 + jj) * 72 + slot * 16];
            uint4 u0 = *(const uint4*)(vr);
            uint4 u1 = *(const uint4*)(vr + 8);
            float vv[16];
            unpack8(u0, vv);
            unpack8(u1, vv + 8);
            float p = p8[jj];
#pragma unroll
            for (int e = 0; e < 16; e++) out[e] += p * vv[e];
        }
    }

    __hip_bfloat16* op = O + base + (size_t)iq * DMODEL + slot * 16;
    __hip_bfloat16 pk[16];
#pragma unroll
    for (int e = 0; e < 16; e++) pk[e] = __float2bfloat16(out[e]);
    *(uint4*)op       = *(uint4*)pk;
    *(uint4*)(op + 8) = *(uint4*)(pk + 8);
}

extern "C" void kernel_launch(void* const* d_in, const int* in_sizes, int n_in,
                              void* d_out, int out_size, void* d_ws, size_t ws_size,
                              hipStream_t stream)
{
    const float* x  = (const float*)d_in[0];
    const float* Wq = (const float*)d_in[1];
    const float* Wk = (const float*)d_in[2];
    const float* Wv = (const float*)d_in[3];
    const float* Wo = (const float*)d_in[4];
    float* out = (float*)d_out;

    const size_t MT = (size_t)BATCH * T_SEQ;          // 4096 rows
    __hip_bfloat16* Qw = (__hip_bfloat16*)d_ws;       // 8 MB each (bf16)
    __hip_bfloat16* Kw = Qw + MT * DMODEL;
    __hip_bfloat16* Vw = Kw + MT * DMODEL;
    __hip_bfloat16* AO = Vw + MT * DMODEL;

    dim3 g1(DMODEL / 128, MT / 128, 3);
    gemm_bt_kernel<true, false><<<g1, 256, 0, stream>>>(
        x, Wq, Wk, Wv, Qw, Kw, Vw, (int)MT, DMODEL, DMODEL);

    l2norm_kernel<<<2048, 256, 0, stream>>>(Qw, Kw);

    dim3 g2(T_SEQ / 64, NHEADS, BATCH);
    attn_kernel<<<g2, 256, 0, stream>>>(Qw, Kw, Vw, AO);

    dim3 g3(DMODEL / 128, MT / 128, 1);
    gemm_bt_kernel<false, true><<<g3, 256, 0, stream>>>(
        AO, Wo, Wo, Wo, out, out, out, (int)MT, DMODEL, DMODEL);
}

// Round 4
// 197.964 us; speedup vs baseline: 2.0277x; 1.1988x over previous
//
#include <hip/hip_runtime.h>
#include <hip/hip_bf16.h>

#define T_SEQ   2048
#define BATCH   2
#define DMODEL  1024
#define NHEADS  16
#define HDIM    64
#define WINDOW  128

typedef __attribute__((ext_vector_type(8))) short bf16x8;
typedef __attribute__((ext_vector_type(4))) float f32x4;

__device__ inline void unpack8(uint4 u, float* f) {
    unsigned int w[4] = {u.x, u.y, u.z, u.w};
#pragma unroll
    for (int i = 0; i < 4; i++) {
        f[2*i]   = __uint_as_float(w[i] << 16);
        f[2*i+1] = __uint_as_float(w[i] & 0xffff0000u);
    }
}

// Load 16 contiguous fp32 elements, convert to packed bf16.
__device__ inline void load16_f32_to_bf16(const float* p, __hip_bfloat16* dst) {
    float4 f0 = *(const float4*)(p);
    float4 f1 = *(const float4*)(p + 4);
    float4 f2 = *(const float4*)(p + 8);
    float4 f3 = *(const float4*)(p + 12);
    float v[16] = {f0.x,f0.y,f0.z,f0.w, f1.x,f1.y,f1.z,f1.w,
                   f2.x,f2.y,f2.z,f2.w, f3.x,f3.y,f3.z,f3.w};
#pragma unroll
    for (int i = 0; i < 16; i++) dst[i] = __float2bfloat16(v[i]);
}

__device__ inline void load16_bf16(const __hip_bfloat16* p, __hip_bfloat16* dst) {
    *(uint4*)dst       = *(const uint4*)p;
    *(uint4*)(dst + 8) = *(const uint4*)(p + 8);
}

// C[M,N] = A[M,K] * W[N,K]^T  (torch Linear). W is always fp32.
// A: fp32 if A_F32 else bf16. C: fp32 if C_F32 else bf16.
template<bool A_F32, bool C_F32>
__global__ __launch_bounds__(256) void gemm_bt_kernel(
    const void* __restrict__ Av,
    const float* __restrict__ W0,
    const float* __restrict__ W1,
    const float* __restrict__ W2,
    void* __restrict__ C0v,
    void* __restrict__ C1v,
    void* __restrict__ C2v,
    int M, int N, int K)
{
    const int z = blockIdx.z;
    const float* W = (z == 0) ? W0 : (z == 1 ? W1 : W2);
    void* Cv = (z == 0) ? C0v : (z == 1 ? C1v : C2v);

    const int n0 = blockIdx.x * 128;
    const int m0 = blockIdx.y * 128;

    __shared__ __hip_bfloat16 As[128 * 40];
    __shared__ __hip_bfloat16 Bs[128 * 40];

    const int t    = threadIdx.x;
    const int r    = t >> 1;
    const int ch   = (t & 1) * 16;

    const int lane = t & 63;
    const int wv   = t >> 6;
    const int wm   = (wv >> 1) * 64;
    const int wn   = (wv & 1) * 64;
    const int lrow = lane & 15;
    const int quad = lane >> 4;

    f32x4 acc[4][4];
#pragma unroll
    for (int i = 0; i < 4; i++)
#pragma unroll
        for (int j = 0; j < 4; j++)
            acc[i][j] = (f32x4){0.f, 0.f, 0.f, 0.f};

    const float* Ap_f = A_F32 ? ((const float*)Av + (size_t)(m0 + r) * K + ch) : nullptr;
    const __hip_bfloat16* Ap_b = A_F32 ? nullptr
                                       : ((const __hip_bfloat16*)Av + (size_t)(m0 + r) * K + ch);
    const float* Wp = W + (size_t)(n0 + r) * K + ch;
    __hip_bfloat16* AsW = &As[r * 40 + ch];
    __hip_bfloat16* BsW = &Bs[r * 40 + ch];

    for (int k0 = 0; k0 < K; k0 += 32) {
        __hip_bfloat16 at[16], bt[16];
        if (A_F32) load16_f32_to_bf16(Ap_f + k0, at);
        else       load16_bf16(Ap_b + k0, at);
        load16_f32_to_bf16(Wp + k0, bt);
        *(uint4*)(AsW)     = *(uint4*)at;
        *(uint4*)(AsW + 8) = *(uint4*)(at + 8);
        *(uint4*)(BsW)     = *(uint4*)bt;
        *(uint4*)(BsW + 8) = *(uint4*)(bt + 8);
        __syncthreads();

        bf16x8 af[4], bfv[4];
#pragma unroll
        for (int mi = 0; mi < 4; mi++)
            af[mi] = *(const bf16x8*)&As[(wm + mi * 16 + lrow) * 40 + quad * 8];
#pragma unroll
        for (int ni = 0; ni < 4; ni++)
            bfv[ni] = *(const bf16x8*)&Bs[(wn + ni * 16 + lrow) * 40 + quad * 8];
#pragma unroll
        for (int mi = 0; mi < 4; mi++)
#pragma unroll
            for (int ni = 0; ni < 4; ni++)
                acc[mi][ni] = __builtin_amdgcn_mfma_f32_16x16x32_bf16(
                    af[mi], bfv[ni], acc[mi][ni], 0, 0, 0);
        __syncthreads();
    }

#pragma unroll
    for (int mi = 0; mi < 4; mi++) {
#pragma unroll
        for (int rr = 0; rr < 4; rr++) {
            int row = m0 + wm + mi * 16 + quad * 4 + rr;
            if (C_F32) {
                float* Crow = (float*)Cv + (size_t)row * N + n0 + wn + lrow;
#pragma unroll
                for (int ni = 0; ni < 4; ni++)
                    Crow[ni * 16] = acc[mi][ni][rr];
            } else {
                __hip_bfloat16* Crow = (__hip_bfloat16*)Cv + (size_t)row * N + n0 + wn + lrow;
#pragma unroll
                for (int ni = 0; ni < 4; ni++)
                    Crow[ni * 16] = __float2bfloat16(acc[mi][ni][rr]);
            }
        }
    }
}

// In-place per-head l2 normalize of Q and K (bf16 ws buffers).
__global__ __launch_bounds__(256) void l2norm_kernel(__hip_bfloat16* Q, __hip_bfloat16* Kb)
{
    int gw   = (blockIdx.x * 256 + threadIdx.x) >> 6;
    int lane = threadIdx.x & 63;
    __hip_bfloat16* buf = (gw < 4096) ? Q : Kb;
    int row = gw & 4095;
    __hip_bfloat16* p = buf + (size_t)row * DMODEL + lane * 16;

    uint4 u0 = *(uint4*)p;
    uint4 u1 = *(uint4*)(p + 8);
    float v[16];
    unpack8(u0, v);
    unpack8(u1, v + 8);
    float ss = 0.f;
#pragma unroll
    for (int i = 0; i < 16; i++) ss += v[i] * v[i];
    ss += __shfl_xor(ss, 1);
    ss += __shfl_xor(ss, 2);
    float inv = 1.0f / fmaxf(sqrtf(ss), 1e-6f);
    __hip_bfloat16 pk[16];
#pragma unroll
    for (int i = 0; i < 16; i++) pk[i] = __float2bfloat16(v[i] * inv);
    *(uint4*)p       = *(uint4*)pk;
    *(uint4*)(p + 8) = *(uint4*)(pk + 8);
}

// MFMA sliding-window attention. Block = 256 thr = one (b,h) x 64-query tile.
// Wave w owns queries [i0+w*16, i0+w*16+16); its keys span [i0+w*16, +144).
// QK^T: A=Q (global, 2 frags), B=K (LDS Ks). Softmax in C-layout registers.
// P -> LDS (A-layout readback, overlaid on dead Ks). PV: A=P, B=Vt (V staged
// transposed so B-frag is a contiguous 16B read).
__global__ __launch_bounds__(256) void attn_kernel(
    const __hip_bfloat16* __restrict__ Q,
    const __hip_bfloat16* __restrict__ K,
    const __hip_bfloat16* __restrict__ V,
    __hip_bfloat16* __restrict__ O)
{
    const int i0 = blockIdx.x * 64;
    const int h  = blockIdx.y;
    const int b  = blockIdx.z;

    __shared__ __hip_bfloat16 Ks[192 * 72];   // keys band; P overlay after QK^T
    __shared__ __hip_bfloat16 Vt[64 * 208];   // V transposed: [dim][key]

    const size_t base = ((size_t)b * T_SEQ) * DMODEL + h * HDIM;
    const int t = threadIdx.x;

    // stage K (row-major, stride 72) and V transposed (stride 208)
    for (int task = t; task < 192 * 8; task += 256) {
        int row = task >> 3;                  // key index rel i0
        int c   = task & 7;                   // 8-dim chunk
        int j   = min(i0 + row, T_SEQ - 1);   // clamp; masked in scores
        *(uint4*)&Ks[row * 72 + c * 8] = *(const uint4*)(K + base + (size_t)j * DMODEL + c * 8);
        uint4 vv = *(const uint4*)(V + base + (size_t)j * DMODEL + c * 8);
        __hip_bfloat16 tmp[8];
        *(uint4*)tmp = vv;
#pragma unroll
        for (int e = 0; e < 8; e++)
            Vt[(c * 8 + e) * 208 + row] = tmp[e];
    }
    // zero Vt pad cols [192,208)
    for (int task = t; task < 64 * 16; task += 256) {
        int rw = task >> 4, cc = task & 15;
        Vt[rw * 208 + 192 + cc] = __float2bfloat16(0.f);
    }
    __syncthreads();

    const int lane = t & 63;
    const int w    = t >> 6;          // wave id = query subtile
    const int col  = lane & 15;
    const int quad = lane >> 4;
    const float slope = exp2f(-8.0f * (float)h / 15.0f);

    // Q fragments straight from global (A-frag: m=col, k=quad*8+j)
    const __hip_bfloat16* qp = Q + base + (size_t)(i0 + w * 16 + col) * DMODEL + quad * 8;
    bf16x8 qf0 = *(const bf16x8*)(qp);
    bf16x8 qf1 = *(const bf16x8*)(qp + 32);

    // QK^T over 9 key tiles of 16
    f32x4 sc[9];
#pragma unroll
    for (int kt = 0; kt < 9; kt++) {
        sc[kt] = (f32x4){0.f, 0.f, 0.f, 0.f};
        const __hip_bfloat16* kr = &Ks[(w * 16 + kt * 16 + col) * 72 + quad * 8];
        bf16x8 kb0 = *(const bf16x8*)(kr);
        bf16x8 kb1 = *(const bf16x8*)(kr + 32);
        sc[kt] = __builtin_amdgcn_mfma_f32_16x16x32_bf16(qf0, kb0, sc[kt], 0, 0, 0);
        sc[kt] = __builtin_amdgcn_mfma_f32_16x16x32_bf16(qf1, kb1, sc[kt], 0, 0, 0);
    }

    // bias + mask + softmax (C layout: key col = col + 16*kt, query row = quad*4+r)
    float mx[4] = {-3e38f, -3e38f, -3e38f, -3e38f};
#pragma unroll
    for (int kt = 0; kt < 9; kt++) {
#pragma unroll
        for (int r = 0; r < 4; r++) {
            int ql  = quad * 4 + r;
            int rel = kt * 16 + col - ql;
            int ka  = i0 + w * 16 + kt * 16 + col;
            bool valid = (rel >= 0) && (rel < WINDOW) && (ka < T_SEQ);
            float v = valid ? (sc[kt][r] - (float)rel * slope) : -1e30f;
            sc[kt][r] = v;
            mx[r] = fmaxf(mx[r], v);
        }
    }
#pragma unroll
    for (int r = 0; r < 4; r++) {
        mx[r] = fmaxf(mx[r], __shfl_xor(mx[r], 1));
        mx[r] = fmaxf(mx[r], __shfl_xor(mx[r], 2));
        mx[r] = fmaxf(mx[r], __shfl_xor(mx[r], 4));
        mx[r] = fmaxf(mx[r], __shfl_xor(mx[r], 8));
    }
    float sm[4] = {0.f, 0.f, 0.f, 0.f};
#pragma unroll
    for (int kt = 0; kt < 9; kt++) {
#pragma unroll
        for (int r = 0; r < 4; r++) {
            float e = __expf(sc[kt][r] - mx[r]);
            sc[kt][r] = e;
            sm[r] += e;
        }
    }
#pragma unroll
    for (int r = 0; r < 4; r++) {
        sm[r] += __shfl_xor(sm[r], 1);
        sm[r] += __shfl_xor(sm[r], 2);
        sm[r] += __shfl_xor(sm[r], 4);
        sm[r] += __shfl_xor(sm[r], 8);
        sm[r] = 1.0f / sm[r];
    }

    // all Ks reads done -> overlay P (per-wave region, stride 168, 160 key cols)
    __syncthreads();
    __hip_bfloat16* Ps = Ks + w * (16 * 168);
#pragma unroll
    for (int kt = 0; kt < 9; kt++)
#pragma unroll
        for (int r = 0; r < 4; r++)
            Ps[(quad * 4 + r) * 168 + kt * 16 + col] = __float2bfloat16(sc[kt][r] * sm[r]);
    // zero pad keys [144,160): 16 q x 16 cols, 4 per lane
#pragma unroll
    for (int i = 0; i < 4; i++)
        Ps[(lane & 15) * 168 + 144 + quad * 4 + i] = __float2bfloat16(0.f);
    __syncthreads();

    // PV: A = P[q][key], B = Vt[dim][key]
    f32x4 o[4];
#pragma unroll
    for (int nd = 0; nd < 4; nd++) o[nd] = (f32x4){0.f, 0.f, 0.f, 0.f};
#pragma unroll
    for (int kc = 0; kc < 5; kc++) {
        bf16x8 pf = *(const bf16x8*)&Ps[col * 168 + kc * 32 + quad * 8];
#pragma unroll
        for (int nd = 0; nd < 4; nd++) {
            bf16x8 vf = *(const bf16x8*)&Vt[(nd * 16 + col) * 208 + w * 16 + kc * 32 + quad * 8];
            o[nd] = __builtin_amdgcn_mfma_f32_16x16x32_bf16(pf, vf, o[nd], 0, 0, 0);
        }
    }

    // write O (C layout: q = quad*4+r, dim = nd*16+col)
#pragma unroll
    for (int r = 0; r < 4; r++) {
        __hip_bfloat16* op = O + base + (size_t)(i0 + w * 16 + quad * 4 + r) * DMODEL + col;
#pragma unroll
        for (int nd = 0; nd < 4; nd++)
            op[nd * 16] = __float2bfloat16(o[nd][r]);
    }
}

extern "C" void kernel_launch(void* const* d_in, const int* in_sizes, int n_in,
                              void* d_out, int out_size, void* d_ws, size_t ws_size,
                              hipStream_t stream)
{
    const float* x  = (const float*)d_in[0];
    const float* Wq = (const float*)d_in[1];
    const float* Wk = (const float*)d_in[2];
    const float* Wv = (const float*)d_in[3];
    const float* Wo = (const float*)d_in[4];
    float* out = (float*)d_out;

    const size_t MT = (size_t)BATCH * T_SEQ;          // 4096 rows
    __hip_bfloat16* Qw = (__hip_bfloat16*)d_ws;       // 8 MB each (bf16)
    __hip_bfloat16* Kw = Qw + MT * DMODEL;
    __hip_bfloat16* Vw = Kw + MT * DMODEL;
    __hip_bfloat16* AO = Vw + MT * DMODEL;

    dim3 g1(DMODEL / 128, MT / 128, 3);
    gemm_bt_kernel<true, false><<<g1, 256, 0, stream>>>(
        x, Wq, Wk, Wv, Qw, Kw, Vw, (int)MT, DMODEL, DMODEL);

    l2norm_kernel<<<2048, 256, 0, stream>>>(Qw, Kw);

    dim3 g2(T_SEQ / 64, NHEADS, BATCH);
    attn_kernel<<<g2, 256, 0, stream>>>(Qw, Kw, Vw, AO);

    dim3 g3(DMODEL / 128, MT / 128, 1);
    gemm_bt_kernel<false, true><<<g3, 256, 0, stream>>>(
        AO, Wo, Wo, Wo, out, out, out, (int)MT, DMODEL, DMODEL);
}

// Round 5
// 173.342 us; speedup vs baseline: 2.3157x; 1.1420x over previous
//
#include <hip/hip_runtime.h>
#include <hip/hip_bf16.h>

#define T_SEQ   2048
#define BATCH   2
#define DMODEL  1024
#define NHEADS  16
#define HDIM    64
#define WINDOW  128

typedef __attribute__((ext_vector_type(8))) short bf16x8;
typedef __attribute__((ext_vector_type(4))) float f32x4;

__device__ inline void unpack8(uint4 u, float* f) {
    unsigned int w[4] = {u.x, u.y, u.z, u.w};
#pragma unroll
    for (int i = 0; i < 4; i++) {
        f[2*i]   = __uint_as_float(w[i] << 16);
        f[2*i+1] = __uint_as_float(w[i] & 0xffff0000u);
    }
}

// async global->LDS 16B per lane; LDS dest is wave-uniform base + lane*16
__device__ inline void gld_lds16(const __hip_bfloat16* g, __hip_bfloat16* l) {
    __builtin_amdgcn_global_load_lds(
        (const __attribute__((address_space(1))) unsigned int*)g,
        (__attribute__((address_space(3))) unsigned int*)l, 16, 0, 0);
}

// fp32 -> bf16 bulk convert: y=0 -> x (4M), y=1..4 -> Wq/Wk/Wv/Wo (1M each)
__global__ __launch_bounds__(256) void cvt_kernel(
    const float* __restrict__ x,  const float* __restrict__ Wq,
    const float* __restrict__ Wk, const float* __restrict__ Wv,
    const float* __restrict__ Wo,
    __hip_bfloat16* __restrict__ xb, __hip_bfloat16* __restrict__ Wb)
{
    const int slot = blockIdx.y;
    const float* src;
    __hip_bfloat16* dst;
    int n;
    if (slot == 0) { src = x; dst = xb; n = 4 * 1024 * 1024; }
    else {
        src = (slot == 1) ? Wq : (slot == 2) ? Wk : (slot == 3) ? Wv : Wo;
        dst = Wb + (size_t)(slot - 1) * 1024 * 1024;
        n = 1024 * 1024;
    }
    int i = (blockIdx.x * 256 + threadIdx.x) * 8;
    if (i >= n) return;
    float4 a = *(const float4*)(src + i);
    float4 b = *(const float4*)(src + i + 4);
    __hip_bfloat16 pk[8] = {
        __float2bfloat16(a.x), __float2bfloat16(a.y),
        __float2bfloat16(a.z), __float2bfloat16(a.w),
        __float2bfloat16(b.x), __float2bfloat16(b.y),
        __float2bfloat16(b.z), __float2bfloat16(b.w)};
    *(uint4*)(dst + i) = *(uint4*)pk;
}

// C[M,N] = A[M,K] * W[N,K]^T, all-bf16 operands, fp32 accum.
// m97-style: 128x128 tile, BK=32, unpadded LDS + global_load_lds dwordx4.
// Chunk swizzle: LDS slot (R,s) holds global chunk (s - (R>>1))&3 so the
// b128 fragment reads are 2-way (free) instead of 4-way banked.
template<bool C_F32>
__global__ __launch_bounds__(256) void gemm_bt_bf16(
    const __hip_bfloat16* __restrict__ A,
    const __hip_bfloat16* __restrict__ W0,
    const __hip_bfloat16* __restrict__ W1,
    const __hip_bfloat16* __restrict__ W2,
    void* __restrict__ C0v, void* __restrict__ C1v, void* __restrict__ C2v,
    int M, int N, int K)
{
    const int z = blockIdx.z;
    const __hip_bfloat16* W = (z == 0) ? W0 : (z == 1 ? W1 : W2);
    void* Cv = (z == 0) ? C0v : (z == 1 ? C1v : C2v);

    const int n0 = blockIdx.x * 128;
    const int m0 = blockIdx.y * 128;

    __shared__ __hip_bfloat16 As[128 * 32];
    __shared__ __hip_bfloat16 Bs[128 * 32];

    const int t    = threadIdx.x;
    const int lane = t & 63;
    const int wv   = t >> 6;

    // staging: wave wv covers rows [wv*32, wv*32+32), 2 insts of 16 rows each
    const int srow = wv * 32 + (lane >> 2);
    const int gc   = ((lane & 3) - (lane >> 3)) & 3;   // swizzled global chunk
    const __hip_bfloat16* Ag = A + (size_t)(m0 + srow) * K + gc * 8;
    const __hip_bfloat16* Wg = W + (size_t)(n0 + srow) * K + gc * 8;
    const size_t row16 = (size_t)16 * K;
    __hip_bfloat16* AsD0 = &As[(wv * 32) * 32];
    __hip_bfloat16* AsD1 = &As[(wv * 32 + 16) * 32];
    __hip_bfloat16* BsD0 = &Bs[(wv * 32) * 32];
    __hip_bfloat16* BsD1 = &Bs[(wv * 32 + 16) * 32];

    const int wm   = (wv >> 1) * 64;
    const int wn   = (wv & 1) * 64;
    const int lrow = lane & 15;
    const int quad = lane >> 4;
    const int slot = ((quad + (lrow >> 1)) & 3) * 8;   // swizzled read slot

    f32x4 acc[4][4];
#pragma unroll
    for (int i = 0; i < 4; i++)
#pragma unroll
        for (int j = 0; j < 4; j++)
            acc[i][j] = (f32x4){0.f, 0.f, 0.f, 0.f};

    for (int k0 = 0; k0 < K; k0 += 32) {
        gld_lds16(Ag + k0,         AsD0);
        gld_lds16(Ag + k0 + row16, AsD1);
        gld_lds16(Wg + k0,         BsD0);
        gld_lds16(Wg + k0 + row16, BsD1);
        __syncthreads();   // compiler emits vmcnt(0) drain before barrier

        bf16x8 af[4], bfv[4];
#pragma unroll
        for (int mi = 0; mi < 4; mi++)
            af[mi] = *(const bf16x8*)&As[(wm + mi * 16 + lrow) * 32 + slot];
#pragma unroll
        for (int ni = 0; ni < 4; ni++)
            bfv[ni] = *(const bf16x8*)&Bs[(wn + ni * 16 + lrow) * 32 + slot];
#pragma unroll
        for (int mi = 0; mi < 4; mi++)
#pragma unroll
            for (int ni = 0; ni < 4; ni++)
                acc[mi][ni] = __builtin_amdgcn_mfma_f32_16x16x32_bf16(
                    af[mi], bfv[ni], acc[mi][ni], 0, 0, 0);
        __syncthreads();
    }

    // epilogue: C/D layout col=lane&15, row=quad*4+reg  [verified m89/m91]
#pragma unroll
    for (int mi = 0; mi < 4; mi++) {
#pragma unroll
        for (int rr = 0; rr < 4; rr++) {
            int row = m0 + wm + mi * 16 + quad * 4 + rr;
            if (C_F32) {
                float* Crow = (float*)Cv + (size_t)row * N + n0 + wn + lrow;
#pragma unroll
                for (int ni = 0; ni < 4; ni++)
                    Crow[ni * 16] = acc[mi][ni][rr];
            } else {
                __hip_bfloat16* Crow = (__hip_bfloat16*)Cv + (size_t)row * N + n0 + wn + lrow;
#pragma unroll
                for (int ni = 0; ni < 4; ni++)
                    Crow[ni * 16] = __float2bfloat16(acc[mi][ni][rr]);
            }
        }
    }
}

// In-place per-head l2 normalize of Q and K (bf16 ws buffers).
__global__ __launch_bounds__(256) void l2norm_kernel(__hip_bfloat16* Q, __hip_bfloat16* Kb)
{
    int gw   = (blockIdx.x * 256 + threadIdx.x) >> 6;
    int lane = threadIdx.x & 63;
    __hip_bfloat16* buf = (gw < 4096) ? Q : Kb;
    int row = gw & 4095;
    __hip_bfloat16* p = buf + (size_t)row * DMODEL + lane * 16;

    uint4 u0 = *(uint4*)p;
    uint4 u1 = *(uint4*)(p + 8);
    float v[16];
    unpack8(u0, v);
    unpack8(u1, v + 8);
    float ss = 0.f;
#pragma unroll
    for (int i = 0; i < 16; i++) ss += v[i] * v[i];
    ss += __shfl_xor(ss, 1);
    ss += __shfl_xor(ss, 2);
    float inv = 1.0f / fmaxf(sqrtf(ss), 1e-6f);
    __hip_bfloat16 pk[16];
#pragma unroll
    for (int i = 0; i < 16; i++) pk[i] = __float2bfloat16(v[i] * inv);
    *(uint4*)p       = *(uint4*)pk;
    *(uint4*)(p + 8) = *(uint4*)(pk + 8);
}

// MFMA sliding-window attention. Block = 256 thr = one (b,h) x 64-query tile.
__global__ __launch_bounds__(256) void attn_kernel(
    const __hip_bfloat16* __restrict__ Q,
    const __hip_bfloat16* __restrict__ K,
    const __hip_bfloat16* __restrict__ V,
    __hip_bfloat16* __restrict__ O)
{
    const int i0 = blockIdx.x * 64;
    const int h  = blockIdx.y;
    const int b  = blockIdx.z;

    __shared__ __hip_bfloat16 Ks[192 * 72];   // keys band; P overlay after QK^T
    __shared__ __hip_bfloat16 Vt[64 * 208];   // V transposed: [dim][key]

    const size_t base = ((size_t)b * T_SEQ) * DMODEL + h * HDIM;
    const int t = threadIdx.x;

    for (int task = t; task < 192 * 8; task += 256) {
        int row = task >> 3;
        int c   = task & 7;
        int j   = min(i0 + row, T_SEQ - 1);
        *(uint4*)&Ks[row * 72 + c * 8] = *(const uint4*)(K + base + (size_t)j * DMODEL + c * 8);
        uint4 vv = *(const uint4*)(V + base + (size_t)j * DMODEL + c * 8);
        __hip_bfloat16 tmp[8];
        *(uint4*)tmp = vv;
#pragma unroll
        for (int e = 0; e < 8; e++)
            Vt[(c * 8 + e) * 208 + row] = tmp[e];
    }
    for (int task = t; task < 64 * 16; task += 256) {
        int rw = task >> 4, cc = task & 15;
        Vt[rw * 208 + 192 + cc] = __float2bfloat16(0.f);
    }
    __syncthreads();

    const int lane = t & 63;
    const int w    = t >> 6;
    const int col  = lane & 15;
    const int quad = lane >> 4;
    const float slope = exp2f(-8.0f * (float)h / 15.0f);

    const __hip_bfloat16* qp = Q + base + (size_t)(i0 + w * 16 + col) * DMODEL + quad * 8;
    bf16x8 qf0 = *(const bf16x8*)(qp);
    bf16x8 qf1 = *(const bf16x8*)(qp + 32);

    f32x4 sc[9];
#pragma unroll
    for (int kt = 0; kt < 9; kt++) {
        sc[kt] = (f32x4){0.f, 0.f, 0.f, 0.f};
        const __hip_bfloat16* kr = &Ks[(w * 16 + kt * 16 + col) * 72 + quad * 8];
        bf16x8 kb0 = *(const bf16x8*)(kr);
        bf16x8 kb1 = *(const bf16x8*)(kr + 32);
        sc[kt] = __builtin_amdgcn_mfma_f32_16x16x32_bf16(qf0, kb0, sc[kt], 0, 0, 0);
        sc[kt] = __builtin_amdgcn_mfma_f32_16x16x32_bf16(qf1, kb1, sc[kt], 0, 0, 0);
    }

    float mx[4] = {-3e38f, -3e38f, -3e38f, -3e38f};
#pragma unroll
    for (int kt = 0; kt < 9; kt++) {
#pragma unroll
        for (int r = 0; r < 4; r++) {
            int ql  = quad * 4 + r;
            int rel = kt * 16 + col - ql;
            int ka  = i0 + w * 16 + kt * 16 + col;
            bool valid = (rel >= 0) && (rel < WINDOW) && (ka < T_SEQ);
            float v = valid ? (sc[kt][r] - (float)rel * slope) : -1e30f;
            sc[kt][r] = v;
            mx[r] = fmaxf(mx[r], v);
        }
    }
#pragma unroll
    for (int r = 0; r < 4; r++) {
        mx[r] = fmaxf(mx[r], __shfl_xor(mx[r], 1));
        mx[r] = fmaxf(mx[r], __shfl_xor(mx[r], 2));
        mx[r] = fmaxf(mx[r], __shfl_xor(mx[r], 4));
        mx[r] = fmaxf(mx[r], __shfl_xor(mx[r], 8));
    }
    float sm[4] = {0.f, 0.f, 0.f, 0.f};
#pragma unroll
    for (int kt = 0; kt < 9; kt++) {
#pragma unroll
        for (int r = 0; r < 4; r++) {
            float e = __expf(sc[kt][r] - mx[r]);
            sc[kt][r] = e;
            sm[r] += e;
        }
    }
#pragma unroll
    for (int r = 0; r < 4; r++) {
        sm[r] += __shfl_xor(sm[r], 1);
        sm[r] += __shfl_xor(sm[r], 2);
        sm[r] += __shfl_xor(sm[r], 4);
        sm[r] += __shfl_xor(sm[r], 8);
        sm[r] = 1.0f / sm[r];
    }

    __syncthreads();
    __hip_bfloat16* Ps = Ks + w * (16 * 168);
#pragma unroll
    for (int kt = 0; kt < 9; kt++)
#pragma unroll
        for (int r = 0; r < 4; r++)
            Ps[(quad * 4 + r) * 168 + kt * 16 + col] = __float2bfloat16(sc[kt][r] * sm[r]);
#pragma unroll
    for (int i = 0; i < 4; i++)
        Ps[(lane & 15) * 168 + 144 + quad * 4 + i] = __float2bfloat16(0.f);
    __syncthreads();

    f32x4 o[4];
#pragma unroll
    for (int nd = 0; nd < 4; nd++) o[nd] = (f32x4){0.f, 0.f, 0.f, 0.f};
#pragma unroll
    for (int kc = 0; kc < 5; kc++) {
        bf16x8 pf = *(const bf16x8*)&Ps[col * 168 + kc * 32 + quad * 8];
#pragma unroll
        for (int nd = 0; nd < 4; nd++) {
            bf16x8 vf = *(const bf16x8*)&Vt[(nd * 16 + col) * 208 + w * 16 + kc * 32 + quad * 8];
            o[nd] = __builtin_amdgcn_mfma_f32_16x16x32_bf16(pf, vf, o[nd], 0, 0, 0);
        }
    }

#pragma unroll
    for (int r = 0; r < 4; r++) {
        __hip_bfloat16* op = O + base + (size_t)(i0 + w * 16 + quad * 4 + r) * DMODEL + col;
#pragma unroll
        for (int nd = 0; nd < 4; nd++)
            op[nd * 16] = __float2bfloat16(o[nd][r]);
    }
}

extern "C" void kernel_launch(void* const* d_in, const int* in_sizes, int n_in,
                              void* d_out, int out_size, void* d_ws, size_t ws_size,
                              hipStream_t stream)
{
    const float* x  = (const float*)d_in[0];
    const float* Wq = (const float*)d_in[1];
    const float* Wk = (const float*)d_in[2];
    const float* Wv = (const float*)d_in[3];
    const float* Wo = (const float*)d_in[4];
    float* out = (float*)d_out;

    const size_t MT = (size_t)BATCH * T_SEQ;          // 4096 rows
    __hip_bfloat16* Qw = (__hip_bfloat16*)d_ws;       // 8 MB each (bf16)
    __hip_bfloat16* Kw = Qw + MT * DMODEL;
    __hip_bfloat16* Vw = Kw + MT * DMODEL;
    __hip_bfloat16* XA = Vw + MT * DMODEL;            // xb (pre-attn) / AO (post-attn)
    __hip_bfloat16* Wb = XA + MT * DMODEL;            // 4 x 1M bf16 weights

    cvt_kernel<<<dim3(2048, 5), 256, 0, stream>>>(x, Wq, Wk, Wv, Wo, XA, Wb);

    dim3 g1(DMODEL / 128, MT / 128, 3);
    gemm_bt_bf16<false><<<g1, 256, 0, stream>>>(
        XA, Wb, Wb + 1024 * 1024, Wb + 2 * 1024 * 1024,
        Qw, Kw, Vw, (int)MT, DMODEL, DMODEL);

    l2norm_kernel<<<2048, 256, 0, stream>>>(Qw, Kw);

    dim3 g2(T_SEQ / 64, NHEADS, BATCH);
    attn_kernel<<<g2, 256, 0, stream>>>(Qw, Kw, Vw, XA);

    dim3 g3(DMODEL / 128, MT / 128, 1);
    gemm_bt_bf16<true><<<g3, 256, 0, stream>>>(
        XA, Wb + 3 * 1024 * 1024, Wb + 3 * 1024 * 1024, Wb + 3 * 1024 * 1024,
        out, out, out, (int)MT, DMODEL, DMODEL);
}

// Round 6
// 157.980 us; speedup vs baseline: 2.5409x; 1.0972x over previous
//
#include <hip/hip_runtime.h>
#include <hip/hip_bf16.h>

#define T_SEQ   2048
#define BATCH   2
#define DMODEL  1024
#define NHEADS  16
#define HDIM    64
#define WINDOW  128

typedef __attribute__((ext_vector_type(8))) short bf16x8;
typedef __attribute__((ext_vector_type(4))) float f32x4;

__device__ inline void unpack8(uint4 u, float* f) {
    unsigned int w[4] = {u.x, u.y, u.z, u.w};
#pragma unroll
    for (int i = 0; i < 4; i++) {
        f[2*i]   = __uint_as_float(w[i] << 16);
        f[2*i+1] = __uint_as_float(w[i] & 0xffff0000u);
    }
}

// async global->LDS 16B per lane; LDS dest is wave-uniform base + lane*16
__device__ inline void gld_lds16(const __hip_bfloat16* g, __hip_bfloat16* l) {
    __builtin_amdgcn_global_load_lds(
        (const __attribute__((address_space(1))) unsigned int*)g,
        (__attribute__((address_space(3))) unsigned int*)l, 16, 0, 0);
}

// fp32 -> bf16 bulk convert: y=0 -> x (4M), y=1..4 -> Wq/Wk/Wv/Wo (1M each)
__global__ __launch_bounds__(256) void cvt_kernel(
    const float* __restrict__ x,  const float* __restrict__ Wq,
    const float* __restrict__ Wk, const float* __restrict__ Wv,
    const float* __restrict__ Wo,
    __hip_bfloat16* __restrict__ xb, __hip_bfloat16* __restrict__ Wb)
{
    const int slot = blockIdx.y;
    const float* src;
    __hip_bfloat16* dst;
    int n;
    if (slot == 0) { src = x; dst = xb; n = 4 * 1024 * 1024; }
    else {
        src = (slot == 1) ? Wq : (slot == 2) ? Wk : (slot == 3) ? Wv : Wo;
        dst = Wb + (size_t)(slot - 1) * 1024 * 1024;
        n = 1024 * 1024;
    }
    int i = (blockIdx.x * 256 + threadIdx.x) * 8;
    if (i >= n) return;
    float4 a = *(const float4*)(src + i);
    float4 b = *(const float4*)(src + i + 4);
    __hip_bfloat16 pk[8] = {
        __float2bfloat16(a.x), __float2bfloat16(a.y),
        __float2bfloat16(a.z), __float2bfloat16(a.w),
        __float2bfloat16(b.x), __float2bfloat16(b.y),
        __float2bfloat16(b.z), __float2bfloat16(b.w)};
    *(uint4*)(dst + i) = *(uint4*)pk;
}

// C[M,N] = A[M,K] * W[N,K]^T, all-bf16 operands, fp32 accum.
// MI=4: 128x128 tile (QKV). MI=2: 64x128 tile (O-proj, 2x blocks for occupancy).
// Unpadded LDS + global_load_lds dwordx4; chunk swizzle keeps b128 reads 2-way.
// For z<2 (Q,K) the per-head l2norm is fused into the epilogue: head width 64
// == wave n-extent, so 4 shfl_xor over col lanes give the full head sum.
template<bool C_F32, int MI>
__global__ __launch_bounds__(256) void gemm_bt_bf16(
    const __hip_bfloat16* __restrict__ A,
    const __hip_bfloat16* __restrict__ W0,
    const __hip_bfloat16* __restrict__ W1,
    const __hip_bfloat16* __restrict__ W2,
    void* __restrict__ C0v, void* __restrict__ C1v, void* __restrict__ C2v,
    int M, int N, int K)
{
    const int z = blockIdx.z;
    const __hip_bfloat16* W = (z == 0) ? W0 : (z == 1 ? W1 : W2);
    void* Cv = (z == 0) ? C0v : (z == 1 ? C1v : C2v);

    const int n0 = blockIdx.x * 128;
    const int m0 = blockIdx.y * (MI * 32);

    __shared__ __hip_bfloat16 As[MI * 32 * 32];
    __shared__ __hip_bfloat16 Bs[128 * 32];

    const int t    = threadIdx.x;
    const int lane = t & 63;
    const int wv   = t >> 6;

    // staging: each gld_lds16 inst covers 16 rows x 32 cols
    const int gc    = ((lane & 3) - (lane >> 3)) & 3;   // swizzled global chunk
    const int srowA = wv * (MI * 8) + (lane >> 2);
    const int srowB = wv * 32 + (lane >> 2);
    const __hip_bfloat16* Ag = A + (size_t)(m0 + srowA) * K + gc * 8;
    const __hip_bfloat16* Wg = W + (size_t)(n0 + srowB) * K + gc * 8;
    const size_t row16 = (size_t)16 * K;
    __hip_bfloat16* AsD0 = &As[(wv * (MI * 8)) * 32];
    __hip_bfloat16* AsD1 = &As[(wv * (MI * 8) + 16) * 32];
    __hip_bfloat16* BsD0 = &Bs[(wv * 32) * 32];
    __hip_bfloat16* BsD1 = &Bs[(wv * 32 + 16) * 32];

    const int wm   = (wv >> 1) * (MI * 16);
    const int wn   = (wv & 1) * 64;
    const int lrow = lane & 15;
    const int quad = lane >> 4;
    const int slot = ((quad + (lrow >> 1)) & 3) * 8;   // swizzled read slot

    f32x4 acc[MI][4];
#pragma unroll
    for (int i = 0; i < MI; i++)
#pragma unroll
        for (int j = 0; j < 4; j++)
            acc[i][j] = (f32x4){0.f, 0.f, 0.f, 0.f};

    for (int k0 = 0; k0 < K; k0 += 32) {
        gld_lds16(Ag + k0, AsD0);
        if (MI == 4) gld_lds16(Ag + k0 + row16, AsD1);
        gld_lds16(Wg + k0,         BsD0);
        gld_lds16(Wg + k0 + row16, BsD1);
        __syncthreads();

        bf16x8 af[MI], bfv[4];
#pragma unroll
        for (int mi = 0; mi < MI; mi++)
            af[mi] = *(const bf16x8*)&As[(wm + mi * 16 + lrow) * 32 + slot];
#pragma unroll
        for (int ni = 0; ni < 4; ni++)
            bfv[ni] = *(const bf16x8*)&Bs[(wn + ni * 16 + lrow) * 32 + slot];
#pragma unroll
        for (int mi = 0; mi < MI; mi++)
#pragma unroll
            for (int ni = 0; ni < 4; ni++)
                acc[mi][ni] = __builtin_amdgcn_mfma_f32_16x16x32_bf16(
                    af[mi], bfv[ni], acc[mi][ni], 0, 0, 0);
        __syncthreads();
    }

    // fused per-head l2norm for Q,K (z<2): head = the wave's 64-col extent
    if (!C_F32 && z != 2) {
#pragma unroll
        for (int mi = 0; mi < MI; mi++) {
#pragma unroll
            for (int rr = 0; rr < 4; rr++) {
                float ss = 0.f;
#pragma unroll
                for (int ni = 0; ni < 4; ni++)
                    ss += acc[mi][ni][rr] * acc[mi][ni][rr];
                ss += __shfl_xor(ss, 1);
                ss += __shfl_xor(ss, 2);
                ss += __shfl_xor(ss, 4);
                ss += __shfl_xor(ss, 8);
                float inv = 1.0f / fmaxf(sqrtf(ss), 1e-6f);
#pragma unroll
                for (int ni = 0; ni < 4; ni++)
                    acc[mi][ni][rr] *= inv;
            }
        }
    }

    // epilogue: C/D layout col=lane&15, row=quad*4+reg  [verified m89/m91]
#pragma unroll
    for (int mi = 0; mi < MI; mi++) {
#pragma unroll
        for (int rr = 0; rr < 4; rr++) {
            int row = m0 + wm + mi * 16 + quad * 4 + rr;
            if (C_F32) {
                float* Crow = (float*)Cv + (size_t)row * N + n0 + wn + lrow;
#pragma unroll
                for (int ni = 0; ni < 4; ni++)
                    Crow[ni * 16] = acc[mi][ni][rr];
            } else {
                __hip_bfloat16* Crow = (__hip_bfloat16*)Cv + (size_t)row * N + n0 + wn + lrow;
#pragma unroll
                for (int ni = 0; ni < 4; ni++)
                    Crow[ni * 16] = __float2bfloat16(acc[mi][ni][rr]);
            }
        }
    }
}

// MFMA sliding-window attention. Block = 256 thr = one (b,h) x 64-query tile.
// Vt: [dim][key] stride 200, key-blocks of 8 placed at swizzled slot
// sigma(b,d) = (b&~7)|((b+(d>>3))&7)  -> uniform banks on both the b128
// transpose writes and the PV b128 reads. Slot 24 = zeroed tail for the
// P==0 key range >=192 (only reachable at w==3).
__global__ __launch_bounds__(256) void attn_kernel(
    const __hip_bfloat16* __restrict__ Q,
    const __hip_bfloat16* __restrict__ K,
    const __hip_bfloat16* __restrict__ V,
    __hip_bfloat16* __restrict__ O)
{
    const int i0 = blockIdx.x * 64;
    const int h  = blockIdx.y;
    const int b  = blockIdx.z;

    __shared__ __hip_bfloat16 Ks[192 * 72];        // keys band; P overlay later
    __shared__ __hip_bfloat16 Vt[64 * 200 + 64];   // V^T, swizzled key blocks

    const size_t base = ((size_t)b * T_SEQ) * DMODEL + h * HDIM;
    const int t = threadIdx.x;

    // K staging: b128 rows, stride 72 (2-way free)
    for (int task = t; task < 192 * 8; task += 256) {
        int row = task >> 3;
        int c   = task & 7;
        int j   = min(i0 + row, T_SEQ - 1);
        *(uint4*)&Ks[row * 72 + c * 8] = *(const uint4*)(K + base + (size_t)j * DMODEL + c * 8);
    }
    // V staging: 8x8 register transpose, swizzled b128 writes
    for (int task = t; task < 192; task += 256) {
        int c  = task & 7;            // dim chunk
        int r0 = (task >> 3) * 8;     // key block start
        int b0 = task >> 3;           // key block index (0..23)
        unsigned short m[8][8];
#pragma unroll
        for (int i = 0; i < 8; i++) {
            int j = min(i0 + r0 + i, T_SEQ - 1);
            uint4 u = *(const uint4*)(V + base + (size_t)j * DMODEL + c * 8);
            unsigned short tmp[8];
            *(uint4*)tmp = u;
#pragma unroll
            for (int e = 0; e < 8; e++) m[e][i] = tmp[e];
        }
#pragma unroll
        for (int e = 0; e < 8; e++) {
            int d  = c * 8 + e;
            int sg = (b0 & ~7) | ((b0 + (d >> 3)) & 7);
            *(uint4*)&Vt[d * 200 + sg * 8] = *(uint4*)m[e];
        }
    }
    // zero slot 24 (tail keys; P is zero there but data must be finite)
    for (int task = t; task < 64; task += 256) {
        uint4 zz = {0, 0, 0, 0};
        *(uint4*)&Vt[task * 200 + 192] = zz;
    }
    __syncthreads();

    const int lane = t & 63;
    const int w    = t >> 6;
    const int col  = lane & 15;
    const int quad = lane >> 4;
    const float slope = exp2f(-8.0f * (float)h / 15.0f);

    const __hip_bfloat16* qp = Q + base + (size_t)(i0 + w * 16 + col) * DMODEL + quad * 8;
    bf16x8 qf0 = *(const bf16x8*)(qp);
    bf16x8 qf1 = *(const bf16x8*)(qp + 32);

    f32x4 sc[9];
#pragma unroll
    for (int kt = 0; kt < 9; kt++) {
        sc[kt] = (f32x4){0.f, 0.f, 0.f, 0.f};
        const __hip_bfloat16* kr = &Ks[(w * 16 + kt * 16 + col) * 72 + quad * 8];
        bf16x8 kb0 = *(const bf16x8*)(kr);
        bf16x8 kb1 = *(const bf16x8*)(kr + 32);
        sc[kt] = __builtin_amdgcn_mfma_f32_16x16x32_bf16(qf0, kb0, sc[kt], 0, 0, 0);
        sc[kt] = __builtin_amdgcn_mfma_f32_16x16x32_bf16(qf1, kb1, sc[kt], 0, 0, 0);
    }

    float mx[4] = {-3e38f, -3e38f, -3e38f, -3e38f};
#pragma unroll
    for (int kt = 0; kt < 9; kt++) {
#pragma unroll
        for (int r = 0; r < 4; r++) {
            int ql  = quad * 4 + r;
            int rel = kt * 16 + col - ql;
            int ka  = i0 + w * 16 + kt * 16 + col;
            bool valid = (rel >= 0) && (rel < WINDOW) && (ka < T_SEQ);
            float v = valid ? (sc[kt][r] - (float)rel * slope) : -1e30f;
            sc[kt][r] = v;
            mx[r] = fmaxf(mx[r], v);
        }
    }
#pragma unroll
    for (int r = 0; r < 4; r++) {
        mx[r] = fmaxf(mx[r], __shfl_xor(mx[r], 1));
        mx[r] = fmaxf(mx[r], __shfl_xor(mx[r], 2));
        mx[r] = fmaxf(mx[r], __shfl_xor(mx[r], 4));
        mx[r] = fmaxf(mx[r], __shfl_xor(mx[r], 8));
    }
    float sm[4] = {0.f, 0.f, 0.f, 0.f};
#pragma unroll
    for (int kt = 0; kt < 9; kt++) {
#pragma unroll
        for (int r = 0; r < 4; r++) {
            float e = __expf(sc[kt][r] - mx[r]);
            sc[kt][r] = e;
            sm[r] += e;
        }
    }
#pragma unroll
    for (int r = 0; r < 4; r++) {
        sm[r] += __shfl_xor(sm[r], 1);
        sm[r] += __shfl_xor(sm[r], 2);
        sm[r] += __shfl_xor(sm[r], 4);
        sm[r] += __shfl_xor(sm[r], 8);
        sm[r] = 1.0f / sm[r];
    }

    // all Ks reads done -> overlay P (per-wave region, stride 168)
    __syncthreads();
    __hip_bfloat16* Ps = Ks + w * (16 * 168);
#pragma unroll
    for (int kt = 0; kt < 9; kt++)
#pragma unroll
        for (int r = 0; r < 4; r++)
            Ps[(quad * 4 + r) * 168 + kt * 16 + col] = __float2bfloat16(sc[kt][r] * sm[r]);
#pragma unroll
    for (int i = 0; i < 4; i++)
        Ps[(lane & 15) * 168 + 144 + quad * 4 + i] = __float2bfloat16(0.f);
    __syncthreads();

    // PV: A = P[q][key], B = Vt[dim][key] (swizzled slots)
    f32x4 o[4];
#pragma unroll
    for (int nd = 0; nd < 4; nd++) o[nd] = (f32x4){0.f, 0.f, 0.f, 0.f};
#pragma unroll
    for (int kc = 0; kc < 5; kc++) {
        bf16x8 pf = *(const bf16x8*)&Ps[col * 168 + kc * 32 + quad * 8];
        int bblk = w * 2 + kc * 4 + quad;
#pragma unroll
        for (int nd = 0; nd < 4; nd++) {
            int d  = nd * 16 + col;
            int sg = (bblk < 24) ? ((bblk & ~7) | ((bblk + (d >> 3)) & 7)) : 24;
            bf16x8 vf = *(const bf16x8*)&Vt[d * 200 + sg * 8];
            o[nd] = __builtin_amdgcn_mfma_f32_16x16x32_bf16(pf, vf, o[nd], 0, 0, 0);
        }
    }

#pragma unroll
    for (int r = 0; r < 4; r++) {
        __hip_bfloat16* op = O + base + (size_t)(i0 + w * 16 + quad * 4 + r) * DMODEL + col;
#pragma unroll
        for (int nd = 0; nd < 4; nd++)
            op[nd * 16] = __float2bfloat16(o[nd][r]);
    }
}

extern "C" void kernel_launch(void* const* d_in, const int* in_sizes, int n_in,
                              void* d_out, int out_size, void* d_ws, size_t ws_size,
                              hipStream_t stream)
{
    const float* x  = (const float*)d_in[0];
    const float* Wq = (const float*)d_in[1];
    const float* Wk = (const float*)d_in[2];
    const float* Wv = (const float*)d_in[3];
    const float* Wo = (const float*)d_in[4];
    float* out = (float*)d_out;

    const size_t MT = (size_t)BATCH * T_SEQ;          // 4096 rows
    __hip_bfloat16* Qw = (__hip_bfloat16*)d_ws;       // 8 MB each (bf16)
    __hip_bfloat16* Kw = Qw + MT * DMODEL;
    __hip_bfloat16* Vw = Kw + MT * DMODEL;
    __hip_bfloat16* XA = Vw + MT * DMODEL;            // xb (pre-attn) / AO (post-attn)
    __hip_bfloat16* Wb = XA + MT * DMODEL;            // 4 x 1M bf16 weights

    cvt_kernel<<<dim3(2048, 5), 256, 0, stream>>>(x, Wq, Wk, Wv, Wo, XA, Wb);

    dim3 g1(DMODEL / 128, MT / 128, 3);
    gemm_bt_bf16<false, 4><<<g1, 256, 0, stream>>>(
        XA, Wb, Wb + 1024 * 1024, Wb + 2 * 1024 * 1024,
        Qw, Kw, Vw, (int)MT, DMODEL, DMODEL);

    dim3 g2(T_SEQ / 64, NHEADS, BATCH);
    attn_kernel<<<g2, 256, 0, stream>>>(Qw, Kw, Vw, XA);

    dim3 g3(DMODEL / 128, MT / 64, 1);
    gemm_bt_bf16<true, 2><<<g3, 256, 0, stream>>>(
        XA, Wb + 3 * 1024 * 1024, Wb + 3 * 1024 * 1024, Wb + 3 * 1024 * 1024,
        out, out, out, (int)MT, DMODEL, DMODEL);
}